// Round 1
// baseline (226.140 us; speedup 1.0000x reference)
//
#include <hip/hip_runtime.h>
#include <stdint.h>

// DecoderCell: single-query masked MHA + clipped single-head logits,
// algebraically folded so node_embeddings [B,N,128] is only streamed
// (never projected through full DxD GEMMs).
//
//   score[b,h,n] = node[b,n,:] . wq[b,h,:],  wq = 0.25 * Wk1[:,h*16:+16] @ q1[h]
//   attn = softmax(masked score) per (b,h)
//   s[b,h,:]  = sum_n attn[b,h,n] * node[b,n,:]
//   mha[h*16+j] = s[b,h,:] . Wv[:,h*16+j]
//   Q2 = mha @ Wout ;  w2 = (Wk2 @ Q2) / sqrt(128)
//   logit[b,n] = mask ? -1e9 : 10*tanh(node[b,n,:] . w2)

#define DD 128
#define NH 8
#define DHD 16
#define TPB 512
#define TILE_ROWS 64
#define ROW_PAD 132   // 128-float rows padded to 132 -> bank stride 4, conflict-free
#define SPAD 9        // score row stride (9 words) -> spreads banks
#define NMAX 1000

__global__ __launch_bounds__(TPB)
void decoder_kernel(const float* __restrict__ node,   // [B,N,128]
                    const float* __restrict__ graph,  // [B,128]
                    const float* __restrict__ ctx,    // [B,130]
                    const void*  __restrict__ maskp,  // [B,N] bool8 or int32 (detected)
                    const float* __restrict__ Wk1,    // [128,128]
                    const float* __restrict__ Wv,
                    const float* __restrict__ Wk2,
                    const float* __restrict__ Wqf,
                    const float* __restrict__ Wout,
                    const float* __restrict__ Wqs,    // [130,128]
                    float* __restrict__ out,          // [B,N]
                    int N)
{
    __shared__ float node_tile[TILE_ROWS * ROW_PAD];   // 33.8 KB
    __shared__ float scores[NMAX * SPAD];              // 36.0 KB
    __shared__ float wq[NH * ROW_PAD];                 // 4.2 KB
    __shared__ float s_lds[NH * ROW_PAD];              // 4.2 KB
    __shared__ float q1[DD];
    __shared__ float mha[DD];
    __shared__ float q2[DD];
    __shared__ float w2[DD];

    const int b    = blockIdx.x;
    const int tid  = threadIdx.x;
    const int lane = tid & 63;
    const int wave = tid >> 6;   // 8 waves == NH heads

    // ---- mask width detection (int32 0/1 vs 1-byte bool), uniform across threads
    const uint32_t* mw = (const uint32_t*)maskp;
    bool mask32 = true;
    #pragma unroll
    for (int i = 0; i < 16; ++i) mask32 = mask32 && (mw[i] <= 1u);
    const int32_t* mi = (const int32_t*)maskp + (size_t)b * N;
    const uint8_t* mb = (const uint8_t*)maskp + (size_t)b * N;

    const float* nodeB = node + (size_t)b * N * DD;

    // ---- Stage 1: q1 = graph[b] @ Wqf + ctx[b] @ Wqs   (128 threads)
    if (tid < DD) {
        const float* ge = graph + (size_t)b * DD;
        const float* sc = ctx   + (size_t)b * (DD + 2);
        float acc = 0.f;
        for (int k = 0; k < DD; ++k)     acc += ge[k] * Wqf[k * DD + tid];
        for (int k = 0; k < DD + 2; ++k) acc += sc[k] * Wqs[k * DD + tid];
        q1[tid] = acc;
    }
    __syncthreads();

    // ---- Stage 2: wq[h][dp] = 0.25 * sum_j Wk1[dp][h*16+j] * q1[h*16+j]
    for (int idx = tid; idx < NH * DD; idx += TPB) {
        const int h = idx >> 7, dp = idx & (DD - 1);
        const float* wrow = Wk1 + dp * DD + h * DHD;
        float acc = 0.f;
        #pragma unroll
        for (int j = 0; j < DHD; ++j) acc += wrow[j] * q1[h * DHD + j];
        wq[h * ROW_PAD + dp] = 0.25f * acc;   // 0.25 = 1/sqrt(16)
    }
    __syncthreads();

    // ---- Pass A: scores[n][h] = node row . wq[h]   (LDS-tiled, 64 rows/tile)
    const int ntiles  = (N + TILE_ROWS - 1) / TILE_ROWS;
    const int n_local = tid >> 3;   // 0..63
    const int hA      = tid & 7;
    for (int t = 0; t < ntiles; ++t) {
        const int n0 = t * TILE_ROWS;
        #pragma unroll
        for (int c = 0; c < 4; ++c) {                 // 64x128 floats, float4-coalesced
            const int idx = c * (TPB * 4) + tid * 4;
            const int row = idx >> 7, col = idx & (DD - 1);
            if (n0 + row < N) {
                const float4 v = *(const float4*)(nodeB + (size_t)(n0 + row) * DD + col);
                *(float4*)&node_tile[row * ROW_PAD + col] = v;
            }
        }
        __syncthreads();
        if (n0 + n_local < N) {
            const float4* nr = (const float4*)&node_tile[n_local * ROW_PAD];
            const float4* wr = (const float4*)&wq[hA * ROW_PAD];
            float acc = 0.f;
            #pragma unroll
            for (int k = 0; k < DD / 4; ++k) {
                const float4 a = nr[k], w = wr[k];
                acc += a.x * w.x + a.y * w.y + a.z * w.z + a.w * w.w;
            }
            scores[(n0 + n_local) * SPAD + hA] = acc;
        }
        __syncthreads();
    }

    // ---- Softmax over n, one wave per head (all in LDS/registers)
    {
        const int h = wave;
        float sm[16];
        #pragma unroll
        for (int k = 0; k < 16; ++k) {
            const int n = lane + 64 * k;
            float v = -1e9f;
            if (n < N) {
                const bool m = mask32 ? (mi[n] != 0) : (mb[n] != 0);
                v = m ? -1e9f : scores[n * SPAD + h];
            }
            sm[k] = v;
        }
        float mx = sm[0];
        #pragma unroll
        for (int k = 1; k < 16; ++k) mx = fmaxf(mx, sm[k]);
        #pragma unroll
        for (int d = 1; d < 64; d <<= 1) mx = fmaxf(mx, __shfl_xor(mx, d));
        float e[16];
        float sum = 0.f;
        #pragma unroll
        for (int k = 0; k < 16; ++k) {
            const int n = lane + 64 * k;
            e[k] = (n < N) ? __expf(sm[k] - mx) : 0.f;
            sum += e[k];
        }
        #pragma unroll
        for (int d = 1; d < 64; d <<= 1) sum += __shfl_xor(sum, d);
        const float rinv = 1.f / sum;
        #pragma unroll
        for (int k = 0; k < 16; ++k) {
            const int n = lane + 64 * k;
            if (n < N) scores[n * SPAD + h] = e[k] * rinv;   // store attn in place
        }
    }
    __syncthreads();

    // ---- Pass B: s[h][:] = sum_n attn[n][h] * node[n][:]   (wave h, lane = col pair)
    {
        const int h = wave;
        const float2* n2 = (const float2*)nodeB;   // row = 64 float2
        float a0 = 0.f, a1 = 0.f;
        #pragma unroll 4
        for (int n = 0; n < N; ++n) {
            const float  at = scores[n * SPAD + h];
            const float2 v  = n2[(size_t)n * 64 + lane];
            a0 += at * v.x;
            a1 += at * v.y;
        }
        s_lds[h * ROW_PAD + 2 * lane]     = a0;
        s_lds[h * ROW_PAD + 2 * lane + 1] = a1;
    }
    __syncthreads();

    // ---- mha[e] = s[h(e)] . Wv[:,e]
    if (tid < DD) {
        const int h = tid >> 4;
        float acc = 0.f;
        for (int dp = 0; dp < DD; ++dp) acc += s_lds[h * ROW_PAD + dp] * Wv[dp * DD + tid];
        mha[tid] = acc;
    }
    __syncthreads();

    // ---- q2 = mha @ Wout
    if (tid < DD) {
        float acc = 0.f;
        for (int e = 0; e < DD; ++e) acc += mha[e] * Wout[e * DD + tid];
        q2[tid] = acc;
    }
    __syncthreads();

    // ---- w2 = (Wk2 @ q2) / sqrt(128)
    if (tid < DD) {
        const float4* row = (const float4*)(Wk2 + tid * DD);
        float acc = 0.f;
        #pragma unroll
        for (int k = 0; k < DD / 4; ++k) {
            const float4 wv = row[k];
            acc += wv.x * q2[4*k] + wv.y * q2[4*k+1] + wv.z * q2[4*k+2] + wv.w * q2[4*k+3];
        }
        w2[tid] = acc * 0.08838834764831845f;  // 1/sqrt(128)
    }
    __syncthreads();

    // ---- Pass C: logits[n] = mask ? -1e9 : 10*tanh(node[n] . w2)   (wave per row)
    {
        const float wa = w2[2 * lane], wb = w2[2 * lane + 1];
        const float2* n2 = (const float2*)nodeB;
        float* outB = out + (size_t)b * N;
        for (int n = wave; n < N; n += NH) {
            const float2 v = n2[(size_t)n * 64 + lane];
            float p = v.x * wa + v.y * wb;
            #pragma unroll
            for (int d = 1; d < 64; d <<= 1) p += __shfl_xor(p, d);
            if (lane == 0) {
                const bool m = mask32 ? (mi[n] != 0) : (mb[n] != 0);
                const float t = 1.f - 2.f / (__expf(2.f * p) + 1.f);  // tanh
                outB[n] = m ? -1e9f : 10.f * t;
            }
        }
    }
}

extern "C" void kernel_launch(void* const* d_in, const int* in_sizes, int n_in,
                              void* d_out, int out_size, void* d_ws, size_t ws_size,
                              hipStream_t stream) {
    (void)n_in; (void)d_ws; (void)ws_size; (void)out_size;
    const float* node  = (const float*)d_in[0];
    const float* graph = (const float*)d_in[1];
    const float* ctx   = (const float*)d_in[2];
    const void*  mask  = d_in[3];
    const float* Wk1   = (const float*)d_in[4];
    const float* Wv    = (const float*)d_in[5];
    const float* Wk2   = (const float*)d_in[6];
    const float* Wqf   = (const float*)d_in[7];
    const float* Wout  = (const float*)d_in[8];
    const float* Wqs   = (const float*)d_in[9];

    const int B = in_sizes[1] / DD;              // graph_embedding [B,128]
    const int N = in_sizes[0] / (B * DD);        // node_embeddings [B,N,128]

    decoder_kernel<<<B, TPB, 0, stream>>>(node, graph, ctx, mask,
                                          Wk1, Wv, Wk2, Wqf, Wout, Wqs,
                                          (float*)d_out, N);
}

// Round 2
// 112.715 us; speedup vs baseline: 2.0063x; 2.0063x over previous
//
#include <hip/hip_runtime.h>
#include <stdint.h>

// DecoderCell, folded algebra (see round 1), now split into a 6-kernel
// pipeline so every heavy phase has thousands of blocks (round-1 kernel was
// latency-bound at 22% occupancy with 1 WG/CU).
//
//   wq[b,h,:] = 0.25 * Wk1[:,h*16:+16] @ (graph@Wqf + ctx@Wqs)[h]   (k0)
//   score[b,h,n] = node[b,n,:] . wq[b,h,:]                          (k1)
//   attn = softmax(masked score)                                    (k2)
//   s[b,h,:] = sum_n attn * node[b,n,:]   (8-way N-split partials)  (k3)
//   mha -> q2 -> w2 = (Wk2@q2)/sqrt(128)                            (k4)
//   logit[b,n] = mask ? -1e9 : 10*tanh(node[b,n,:] . w2)            (k5)

#define DD 128
#define NH 8
#define DHD 16
#define NS 8
#define NMAX_PAD 1024
#define TILE 64
#define RP 132

__device__ __forceinline__ bool detect_mask32(const void* maskp) {
    // int32 0/1 mask -> first 16 words all <=1; packed bool8 -> astronomically unlikely
    const uint32_t* mw = (const uint32_t*)maskp;
    bool m32 = true;
    #pragma unroll
    for (int i = 0; i < 16; ++i) m32 = m32 && (mw[i] <= 1u);
    return m32;
}

// ---------------- k0: per-head folded query ----------------
__global__ __launch_bounds__(128)
void k0_prep(const float* __restrict__ graph, const float* __restrict__ ctx,
             const float* __restrict__ Wk1, const float* __restrict__ Wqf,
             const float* __restrict__ Wqs, float* __restrict__ wq_ws)
{
    __shared__ float q1[DD];
    const int b = blockIdx.x, tid = threadIdx.x;
    const float* ge = graph + (size_t)b * DD;
    const float* sc = ctx + (size_t)b * (DD + 2);
    float acc = 0.f;
    for (int k = 0; k < DD; ++k)     acc += ge[k] * Wqf[k * DD + tid];
    for (int k = 0; k < DD + 2; ++k) acc += sc[k] * Wqs[k * DD + tid];
    q1[tid] = acc;
    __syncthreads();
    const float* wrow = Wk1 + (size_t)tid * DD;   // row dp = tid
    #pragma unroll
    for (int h = 0; h < NH; ++h) {
        float a = 0.f;
        #pragma unroll
        for (int j = 0; j < DHD; ++j) a += wrow[h * DHD + j] * q1[h * DHD + j];
        wq_ws[(size_t)b * NH * DD + h * DD + tid] = 0.25f * a;  // 1/sqrt(16)
    }
}

// ---------------- k1: scores (the HBM pass) ----------------
__global__ __launch_bounds__(512)
void k1_scores(const float* __restrict__ node, const float* __restrict__ wq_ws,
               float* __restrict__ attn_ws, int N)
{
    __shared__ float tile[TILE * RP];   // 33.8 KB
    __shared__ float wq_l[NH * RP];     // 4.2 KB
    const int b = blockIdx.y, tid = threadIdx.x;
    const int base = blockIdx.x * 128;
    const float* nodeB = node + (size_t)b * N * DD;

    for (int i = tid; i < NH * DD; i += 512) {
        const int h = i >> 7, dp = i & 127;
        wq_l[h * RP + dp] = wq_ws[(size_t)b * NH * DD + h * DD + dp];
    }
    __syncthreads();

    const int n_local = tid >> 3, hA = tid & 7;
    for (int t = 0; t < 2; ++t) {
        const int n0 = base + t * TILE;
        #pragma unroll
        for (int c = 0; c < 4; ++c) {
            const int idx = c * (512 * 4) + tid * 4;
            const int row = idx >> 7, col = idx & 127;
            if (n0 + row < N)
                *(float4*)&tile[row * RP + col] =
                    *(const float4*)(nodeB + (size_t)(n0 + row) * DD + col);
        }
        __syncthreads();
        if (n0 + n_local < N) {
            const float4* nr = (const float4*)&tile[n_local * RP];
            const float4* wr = (const float4*)&wq_l[hA * RP];
            float acc = 0.f;
            #pragma unroll
            for (int k = 0; k < 32; ++k) {
                const float4 a = nr[k], w = wr[k];
                acc += a.x * w.x + a.y * w.y + a.z * w.z + a.w * w.w;
            }
            attn_ws[(size_t)b * NH * NMAX_PAD + hA * NMAX_PAD + (n0 + n_local)] = acc;
        }
        __syncthreads();
    }
}

// ---------------- k2: mask + softmax per (b,h) ----------------
__global__ __launch_bounds__(512)
void k2_softmax(const void* __restrict__ maskp, float* __restrict__ attn_ws, int N)
{
    const int b = blockIdx.x, tid = threadIdx.x, lane = tid & 63, h = tid >> 6;
    const bool m32 = detect_mask32(maskp);
    const int32_t* mi = (const int32_t*)maskp + (size_t)b * N;
    const uint8_t* mb = (const uint8_t*)maskp + (size_t)b * N;
    float* arow = attn_ws + (size_t)b * NH * NMAX_PAD + h * NMAX_PAD;

    float sm[16];
    #pragma unroll
    for (int k = 0; k < 16; ++k) {
        const int n = lane + 64 * k;
        float v = -1e30f;
        if (n < N) {
            const bool m = m32 ? (mi[n] != 0) : (mb[n] != 0);
            v = m ? -1e9f : arow[n];
        }
        sm[k] = v;
    }
    float mx = sm[0];
    #pragma unroll
    for (int k = 1; k < 16; ++k) mx = fmaxf(mx, sm[k]);
    #pragma unroll
    for (int d = 1; d < 64; d <<= 1) mx = fmaxf(mx, __shfl_xor(mx, d));
    float e[16], sum = 0.f;
    #pragma unroll
    for (int k = 0; k < 16; ++k) {
        e[k] = __expf(sm[k] - mx);
        sum += e[k];
    }
    #pragma unroll
    for (int d = 1; d < 64; d <<= 1) sum += __shfl_xor(sum, d);
    const float rinv = 1.f / sum;
    #pragma unroll
    for (int k = 0; k < 16; ++k) {
        const int n = lane + 64 * k;
        if (n < N) arow[n] = e[k] * rinv;
    }
}

// ---------------- k3: s partials, N split NS ways ----------------
__global__ __launch_bounds__(256)
void k3_spart(const float* __restrict__ node, const float* __restrict__ attn_ws,
              float* __restrict__ spart_ws, int N)
{
    __shared__ float at_l[NH * 128];      // attn slice (rows <= 128)
    __shared__ float red[4 * NH * DD];    // 16 KB
    const int b = blockIdx.y, j = blockIdx.x, tid = threadIdx.x;
    const int rows = (N + NS - 1) / NS;
    const int n0 = j * rows;
    const int nrows = min(rows, N - n0);

    for (int h = 0; h < NH; ++h)
        for (int r = tid; r < nrows; r += 256)
            at_l[h * 128 + r] = attn_ws[(size_t)b * NH * NMAX_PAD + h * NMAX_PAD + n0 + r];
    __syncthreads();

    const float* nodeB = node + (size_t)b * N * DD;
    const int c = tid & 63, r0 = tid >> 6;
    float2 acc[NH];
    #pragma unroll
    for (int h = 0; h < NH; ++h) acc[h] = make_float2(0.f, 0.f);
    for (int r = r0; r < nrows; r += 4) {
        const float2 v = *(const float2*)(nodeB + (size_t)(n0 + r) * DD + 2 * c);
        #pragma unroll
        for (int h = 0; h < NH; ++h) {
            const float w = at_l[h * 128 + r];   // wave-uniform broadcast
            acc[h].x += w * v.x;
            acc[h].y += w * v.y;
        }
    }
    #pragma unroll
    for (int h = 0; h < NH; ++h) {
        red[(r0 * NH + h) * DD + 2 * c]     = acc[h].x;
        red[(r0 * NH + h) * DD + 2 * c + 1] = acc[h].y;
    }
    __syncthreads();
    for (int o = tid; o < NH * DD; o += 256) {
        const float s = red[o] + red[NH * DD + o] + red[2 * NH * DD + o] + red[3 * NH * DD + o];
        spart_ws[((size_t)b * NS + j) * NH * DD + o] = s;
    }
}

// ---------------- k4: reduce partials + mha + q2 + w2 ----------------
__global__ __launch_bounds__(128)
void k4_head(const float* __restrict__ spart_ws, const float* __restrict__ Wv,
             const float* __restrict__ Wout, const float* __restrict__ Wk2,
             float* __restrict__ w2_ws)
{
    __shared__ float s_l[NH * DD];
    __shared__ float mha_l[DD];
    __shared__ float q2_l[DD];
    const int b = blockIdx.x, tid = threadIdx.x;
    const float* sp = spart_ws + (size_t)b * NS * NH * DD;
    for (int o = tid; o < NH * DD; o += 128) {
        float s = 0.f;
        #pragma unroll
        for (int j = 0; j < NS; ++j) s += sp[j * NH * DD + o];
        s_l[o] = s;
    }
    __syncthreads();
    {
        const int h = tid >> 4;
        float a = 0.f;
        for (int dp = 0; dp < DD; ++dp) a += s_l[h * DD + dp] * Wv[dp * DD + tid];
        mha_l[tid] = a;
    }
    __syncthreads();
    {
        float a = 0.f;
        for (int e = 0; e < DD; ++e) a += mha_l[e] * Wout[e * DD + tid];
        q2_l[tid] = a;
    }
    __syncthreads();
    {
        const float4* row = (const float4*)(Wk2 + (size_t)tid * DD);
        float a = 0.f;
        #pragma unroll
        for (int k = 0; k < 32; ++k) {
            const float4 w = row[k];
            a += w.x * q2_l[4*k] + w.y * q2_l[4*k+1] + w.z * q2_l[4*k+2] + w.w * q2_l[4*k+3];
        }
        w2_ws[(size_t)b * DD + tid] = a * 0.08838834764831845f;  // 1/sqrt(128)
    }
}

// ---------------- k5: logits ----------------
__global__ __launch_bounds__(256)
void k5_logits(const float* __restrict__ node, const float* __restrict__ w2_ws,
               const void* __restrict__ maskp, float* __restrict__ out, int N)
{
    const int b = blockIdx.y, j = blockIdx.x, tid = threadIdx.x;
    const int rows = (N + NS - 1) / NS;
    const int n0 = j * rows;
    const int nend = min(n0 + rows, N);
    const bool m32 = detect_mask32(maskp);
    const int32_t* mi = (const int32_t*)maskp + (size_t)b * N;
    const uint8_t* mb = (const uint8_t*)maskp + (size_t)b * N;
    const int sub = tid & 7, rr = tid >> 3;

    const float4* wv = (const float4*)(w2_ws + (size_t)b * DD + sub * 16);
    const float4 w0 = wv[0], w1 = wv[1], w2v = wv[2], w3 = wv[3];
    const float* nodeB = node + (size_t)b * N * DD;
    float* outB = out + (size_t)b * N;

    for (int n = n0 + rr; n < nend; n += 32) {
        const float4* nr = (const float4*)(nodeB + (size_t)n * DD + sub * 16);
        const float4 a0 = nr[0], a1 = nr[1], a2 = nr[2], a3 = nr[3];
        float p = a0.x*w0.x + a0.y*w0.y + a0.z*w0.z + a0.w*w0.w
                + a1.x*w1.x + a1.y*w1.y + a1.z*w1.z + a1.w*w1.w
                + a2.x*w2v.x + a2.y*w2v.y + a2.z*w2v.z + a2.w*w2v.w
                + a3.x*w3.x + a3.y*w3.y + a3.z*w3.z + a3.w*w3.w;
        p += __shfl_xor(p, 1);
        p += __shfl_xor(p, 2);
        p += __shfl_xor(p, 4);
        if (sub == 0) {
            const bool m = m32 ? (mi[n] != 0) : (mb[n] != 0);
            const float t = 1.f - 2.f / (__expf(2.f * p) + 1.f);  // tanh
            outB[n] = m ? -1e9f : 10.f * t;
        }
    }
}

// ================ fallback: round-1 monolithic kernel ================
#define TPB 512
#define NMAX 1000
#define SPAD 9

__global__ __launch_bounds__(TPB)
void decoder_fallback(const float* __restrict__ node, const float* __restrict__ graph,
                      const float* __restrict__ ctx, const void* __restrict__ maskp,
                      const float* __restrict__ Wk1, const float* __restrict__ Wv,
                      const float* __restrict__ Wk2, const float* __restrict__ Wqf,
                      const float* __restrict__ Wout, const float* __restrict__ Wqs,
                      float* __restrict__ out, int N)
{
    __shared__ float node_tile[TILE * RP];
    __shared__ float scores[NMAX * SPAD];
    __shared__ float wq[NH * RP];
    __shared__ float s_lds[NH * RP];
    __shared__ float q1[DD];
    __shared__ float mha[DD];
    __shared__ float q2[DD];
    __shared__ float w2[DD];

    const int b = blockIdx.x, tid = threadIdx.x, lane = tid & 63, wave = tid >> 6;
    const bool mask32 = detect_mask32(maskp);
    const int32_t* mi = (const int32_t*)maskp + (size_t)b * N;
    const uint8_t* mb = (const uint8_t*)maskp + (size_t)b * N;
    const float* nodeB = node + (size_t)b * N * DD;

    if (tid < DD) {
        const float* ge = graph + (size_t)b * DD;
        const float* sc = ctx + (size_t)b * (DD + 2);
        float acc = 0.f;
        for (int k = 0; k < DD; ++k)     acc += ge[k] * Wqf[k * DD + tid];
        for (int k = 0; k < DD + 2; ++k) acc += sc[k] * Wqs[k * DD + tid];
        q1[tid] = acc;
    }
    __syncthreads();
    for (int idx = tid; idx < NH * DD; idx += TPB) {
        const int h = idx >> 7, dp = idx & (DD - 1);
        const float* wrow = Wk1 + dp * DD + h * DHD;
        float acc = 0.f;
        #pragma unroll
        for (int j = 0; j < DHD; ++j) acc += wrow[j] * q1[h * DHD + j];
        wq[h * RP + dp] = 0.25f * acc;
    }
    __syncthreads();
    const int ntiles = (N + TILE - 1) / TILE;
    const int n_local = tid >> 3, hA = tid & 7;
    for (int t = 0; t < ntiles; ++t) {
        const int n0 = t * TILE;
        #pragma unroll
        for (int c = 0; c < 4; ++c) {
            const int idx = c * (TPB * 4) + tid * 4;
            const int row = idx >> 7, col = idx & (DD - 1);
            if (n0 + row < N)
                *(float4*)&node_tile[row * RP + col] =
                    *(const float4*)(nodeB + (size_t)(n0 + row) * DD + col);
        }
        __syncthreads();
        if (n0 + n_local < N) {
            const float4* nr = (const float4*)&node_tile[n_local * RP];
            const float4* wr = (const float4*)&wq[hA * RP];
            float acc = 0.f;
            #pragma unroll
            for (int k = 0; k < DD / 4; ++k) {
                const float4 a = nr[k], w = wr[k];
                acc += a.x * w.x + a.y * w.y + a.z * w.z + a.w * w.w;
            }
            scores[(n0 + n_local) * SPAD + hA] = acc;
        }
        __syncthreads();
    }
    {
        const int h = wave;
        float sm[16];
        #pragma unroll
        for (int k = 0; k < 16; ++k) {
            const int n = lane + 64 * k;
            float v = -1e9f;
            if (n < N) {
                const bool m = mask32 ? (mi[n] != 0) : (mb[n] != 0);
                v = m ? -1e9f : scores[n * SPAD + h];
            }
            sm[k] = v;
        }
        float mx = sm[0];
        #pragma unroll
        for (int k = 1; k < 16; ++k) mx = fmaxf(mx, sm[k]);
        #pragma unroll
        for (int d = 1; d < 64; d <<= 1) mx = fmaxf(mx, __shfl_xor(mx, d));
        float e[16];
        float sum = 0.f;
        #pragma unroll
        for (int k = 0; k < 16; ++k) {
            const int n = lane + 64 * k;
            e[k] = (n < N) ? __expf(sm[k] - mx) : 0.f;
            sum += e[k];
        }
        #pragma unroll
        for (int d = 1; d < 64; d <<= 1) sum += __shfl_xor(sum, d);
        const float rinv = 1.f / sum;
        #pragma unroll
        for (int k = 0; k < 16; ++k) {
            const int n = lane + 64 * k;
            if (n < N) scores[n * SPAD + h] = e[k] * rinv;
        }
    }
    __syncthreads();
    {
        const int h = wave;
        const float2* n2 = (const float2*)nodeB;
        float a0 = 0.f, a1 = 0.f;
        #pragma unroll 4
        for (int n = 0; n < N; ++n) {
            const float at = scores[n * SPAD + h];
            const float2 v = n2[(size_t)n * 64 + lane];
            a0 += at * v.x;
            a1 += at * v.y;
        }
        s_lds[h * RP + 2 * lane] = a0;
        s_lds[h * RP + 2 * lane + 1] = a1;
    }
    __syncthreads();
    if (tid < DD) {
        const int h = tid >> 4;
        float acc = 0.f;
        for (int dp = 0; dp < DD; ++dp) acc += s_lds[h * RP + dp] * Wv[dp * DD + tid];
        mha[tid] = acc;
    }
    __syncthreads();
    if (tid < DD) {
        float acc = 0.f;
        for (int e = 0; e < DD; ++e) acc += mha[e] * Wout[e * DD + tid];
        q2[tid] = acc;
    }
    __syncthreads();
    if (tid < DD) {
        const float4* row = (const float4*)(Wk2 + tid * DD);
        float acc = 0.f;
        #pragma unroll
        for (int k = 0; k < DD / 4; ++k) {
            const float4 wv = row[k];
            acc += wv.x * q2[4*k] + wv.y * q2[4*k+1] + wv.z * q2[4*k+2] + wv.w * q2[4*k+3];
        }
        w2[tid] = acc * 0.08838834764831845f;
    }
    __syncthreads();
    {
        const float wa = w2[2 * lane], wb = w2[2 * lane + 1];
        const float2* n2 = (const float2*)nodeB;
        float* outB = out + (size_t)b * N;
        for (int n = wave; n < N; n += NH) {
            const float2 v = n2[(size_t)n * 64 + lane];
            float p = v.x * wa + v.y * wb;
            #pragma unroll
            for (int d = 1; d < 64; d <<= 1) p += __shfl_xor(p, d);
            if (lane == 0) {
                const bool m = mask32 ? (mi[n] != 0) : (mb[n] != 0);
                const float t = 1.f - 2.f / (__expf(2.f * p) + 1.f);
                outB[n] = m ? -1e9f : 10.f * t;
            }
        }
    }
}

extern "C" void kernel_launch(void* const* d_in, const int* in_sizes, int n_in,
                              void* d_out, int out_size, void* d_ws, size_t ws_size,
                              hipStream_t stream) {
    (void)n_in; (void)out_size;
    const float* node  = (const float*)d_in[0];
    const float* graph = (const float*)d_in[1];
    const float* ctx   = (const float*)d_in[2];
    const void*  mask  = d_in[3];
    const float* Wk1   = (const float*)d_in[4];
    const float* Wv    = (const float*)d_in[5];
    const float* Wk2   = (const float*)d_in[6];
    const float* Wqf   = (const float*)d_in[7];
    const float* Wout  = (const float*)d_in[8];
    const float* Wqs   = (const float*)d_in[9];

    const int B = in_sizes[1] / DD;
    const int N = in_sizes[0] / (B * DD);

    // workspace layout (floats)
    const size_t off_wq    = 0;
    const size_t off_attn  = off_wq + (size_t)B * NH * DD;
    const size_t off_spart = off_attn + (size_t)B * NH * NMAX_PAD;
    const size_t off_w2    = off_spart + (size_t)B * NS * NH * DD;
    const size_t need_f    = off_w2 + (size_t)B * DD;

    if (N <= NMAX_PAD && ws_size >= need_f * sizeof(float)) {
        float* ws    = (float*)d_ws;
        float* wq_ws    = ws + off_wq;
        float* attn_ws  = ws + off_attn;
        float* spart_ws = ws + off_spart;
        float* w2_ws    = ws + off_w2;

        k0_prep<<<B, 128, 0, stream>>>(graph, ctx, Wk1, Wqf, Wqs, wq_ws);
        k1_scores<<<dim3((N + 127) / 128, B), 512, 0, stream>>>(node, wq_ws, attn_ws, N);
        k2_softmax<<<B, 512, 0, stream>>>(mask, attn_ws, N);
        k3_spart<<<dim3(NS, B), 256, 0, stream>>>(node, attn_ws, spart_ws, N);
        k4_head<<<B, 128, 0, stream>>>(spart_ws, Wv, Wout, Wk2, w2_ws);
        k5_logits<<<dim3(NS, B), 256, 0, stream>>>(node, w2_ws, mask, (float*)d_out, N);
    } else {
        decoder_fallback<<<B, TPB, 0, stream>>>(node, graph, ctx, mask,
                                                Wk1, Wv, Wk2, Wqf, Wout, Wqs,
                                                (float*)d_out, N);
    }
}